// Round 3
// baseline (18049.858 us; speedup 1.0000x reference)
//
#include <hip/hip_runtime.h>
#include <math.h>

#define HDIM 1024
#define BDIM 64
#define TDIM 512
#define KIN  128
#define NBLK 256
#define NTHR 1024           // 16 waves
#define FRAME (HDIM * BDIM) // halfs per ring frame (2-deep rings, as r9)

typedef _Float16 f16;
typedef __attribute__((ext_vector_type(2))) _Float16 f16x2;
typedef __attribute__((ext_vector_type(8))) _Float16 f16x8;
typedef __attribute__((ext_vector_type(4))) float f32x4;
typedef __attribute__((ext_vector_type(4))) unsigned u32x4;

#define MFMA16(a, b, c) __builtin_amdgcn_mfma_f32_16x16x32_f16((a), (b), (c), 0, 0, 0)

__device__ __forceinline__ float sigm(float x) { return 1.0f / (1.0f + expf(-x)); }

// ---------------------------------------------------------------------------
// Octet ring layout (halfs): idx(k, m) = (k>>3)*512 + m*8 + (k&7).
// r11 change: consumers read the rings with PLAIN CACHEABLE loads (L1+L2
// allowed) guarded by a once-per-superstep system-scope acquire fence
// (buffer_inv sc0 sc1) issued after the tagA poll. Producers still publish
// with sc0sc1 write-through stores + vmcnt drain before the tag store, so
// any post-invalidate cache fill observes fresh data from L3. This converts
// the 64 MB/superstep L3 multicast (the measured 4.1us/step BW wall) into
// an L2-served broadcast (~2-6 MB/step from L3).
// ---------------------------------------------------------------------------
__device__ __forceinline__ f16x8 ld_ca(const f16* p) {   // cacheable ring load
    f16x8 r;
    asm volatile("global_load_dwordx4 %0, %1, off"
                 : "=v"(r) : "v"(p) : "memory");
    return r;
}
#define VM_WAIT8(r0, r1, r2, r3, r4, r5, r6, r7)                         \
    asm volatile("s_waitcnt vmcnt(0)"                                    \
                 : "+v"(r0), "+v"(r1), "+v"(r2), "+v"(r3),               \
                   "+v"(r4), "+v"(r5), "+v"(r6), "+v"(r7))

__device__ __forceinline__ void st_cg8(f16* p, uint2 v) {
    asm volatile("global_store_dwordx2 %0, %1, off sc0 sc1"
                 :: "v"(p), "v"(v) : "memory");
}
#define VM_DRAIN() asm volatile("s_waitcnt vmcnt(0)" ::: "memory")

// Acquire: drain + buffer_inv sc0 sc1 (invalidate L1+L2) via the builtin so
// codegen matches the gfx950 memory model exactly.
#define RING_ACQUIRE() __builtin_amdgcn_fence(__ATOMIC_ACQUIRE, "")

// ---------------------------------------------------------------------------
// Tag sync: tag[bid] (4B, contiguous 1KB array per ring) = published step
// tag value, monotone, plain sc0sc1 store by producer lane0 (no atomic RMW,
// no contention). Poller = one full wave: 64 lanes x dwordx4 = all 256 tags
// in ONE coalesced 1KB read per poll round; exit when min >= target.
// ---------------------------------------------------------------------------
__device__ __forceinline__ void tag_pub(unsigned* tag, unsigned v) {
    asm volatile("global_store_dword %0, %1, off sc0 sc1"
                 :: "v"(tag), "v"(v) : "memory");
}
__device__ __forceinline__ void tag_poll(const unsigned* tags, int lane,
                                         unsigned tgt) {
    const unsigned* p = tags + lane * 4;
    for (;;) {
        u32x4 t;
        asm volatile("global_load_dwordx4 %0, %1, off sc0 sc1\n\t"
                     "s_waitcnt vmcnt(0)"
                     : "=v"(t) : "v"(p) : "memory");
        bool ok = (t.x >= tgt) && (t.y >= tgt) && (t.z >= tgt) && (t.w >= tgt);
        if (__all(ok)) break;
        __builtin_amdgcn_s_sleep(1);
    }
}

// ---------------------------------------------------------------------------
__global__ void cvt_w(const float* __restrict__ src, f16* __restrict__ dst, int n2) {
    int i = blockIdx.x * blockDim.x + threadIdx.x;
    if (i < n2) {
        float2 a = ((const float2*)src)[i];
        f16x2 o = {(f16)a.x, (f16)a.y};
        ((f16x2*)dst)[i] = o;
    }
}

// x[b][t][k] fp32 -> xP[t][b][k] fp16
__global__ void cvt_x(const float* __restrict__ x, f16* __restrict__ xP) {
    int P = blockIdx.x * blockDim.x + threadIdx.x;    // pair index
    if (P >= TDIM * BDIM * (KIN / 2)) return;
    int kp = P & 63;
    int b  = (P >> 6) & 63;
    int t  = P >> 12;
    float2 v = ((const float2*)x)[((size_t)b * TDIM + t) * (KIN / 2) + kp];
    f16x2 o = {(f16)v.x, (f16)v.y};
    ((f16x2*)xP)[((size_t)t * BDIM + b) * (KIN / 2) + kp] = o;
}

// ---------------------------------------------------------------------------
// Fused 2-layer LSTM — r9 compute/pipeline structure (256 blocks x 16 waves,
// 4 cols/block, octet layout, 2-deep rings, LDS-staged coalesced publishes,
// per-block tag stores + wave-parallel coalesced tag polls).
// r11: acquire-fence + cached ring reads (see header comment above).
// Tag convention: after publishing h1^{(t)}: tagA[bid] = t+2 (init t=-1 -> 1);
//                 after publishing h2^{(t)}: tagB[bid] = t+2.
// Waits: top of s needs h1^{(s-1)} -> tagA >= s+1;
//        mid-body needs h2^{(s-2)} -> tagB >= s.
// Staleness safety: ring frame addresses are re-read every 2 supersteps; the
// top-of-superstep fence (after tagA poll, before ANY ring/xP read) kills all
// L1/L2 copies cached at step s-2 (and pre-kernel leftovers at s=0). ring2's
// current frame is untouched between the fence and the tagB-gated A2 reads,
// and tagB visibility implies the data reached L3 (producer drains vmcnt
// before tag_pub), so every post-fence fill is fresh.
// ---------------------------------------------------------------------------
__global__ void __launch_bounds__(NTHR, 4) lstm_fused(
    const f16* __restrict__ xP,
    const f16* __restrict__ Wc0, const f16* __restrict__ Wh0,
    const float* __restrict__ bih0, const float* __restrict__ bhh0,
    const f16* __restrict__ Wc1, const f16* __restrict__ Wh1,
    const float* __restrict__ bih1, const float* __restrict__ bhh1,
    f16* ring1, f16* ring2, unsigned* tagA, unsigned* tagB) {

    __shared__ float red[32 * 324 + 16];          // ~41.6 KB padded slots
    __shared__ __align__(16) f16 hbuf1[BDIM * 4]; // owner h1 staging
    __shared__ __align__(16) f16 hbuf2[BDIM * 4];

    const int tid  = threadIdx.x;
    const int lane = tid & 63;
    const int w    = __builtin_amdgcn_readfirstlane(tid >> 6);   // 0..15
    const int bid  = (int)blockIdx.x;
    const int iu4  = __builtin_amdgcn_readfirstlane(bid * 4);

    const int n    = lane & 15;
    const int quad = lane >> 4;
    const int am   = lane & 15;
    const int wrow = iu4 + (n >> 2) + (n & 3) * HDIM;

    // block's h region in octet layout
    const int oct4 = iu4 >> 3;        // octet index of block's 4 cols
    const int coff = iu4 & 7;         // 0 or 4 within octet

    // ---- preload stationary weight fragments ----
    f16x8 B1x;
    f16x8 B1h[2], B2i[2], B2h[2];
    {
        const int kq = quad * 8;
        if (w < 4)
            B1x = *(const f16x8*)(Wc0 + (size_t)wrow * KIN + w * 32 + kq);
        #pragma unroll
        for (int j = 0; j < 2; ++j) {
            const int ks = (2 * w + j) * 32 + kq;
            B1h[j] = *(const f16x8*)(Wh0 + (size_t)wrow * HDIM + ks);
            B2i[j] = *(const f16x8*)(Wc1 + (size_t)wrow * HDIM + ks);
            B2h[j] = *(const f16x8*)(Wh1 + (size_t)wrow * HDIM + ks);
        }
    }

    // ---- owner state (waves 0..3: col icol = iu4 + w, batch = lane) ----
    float bias1[4], bias2[4];
    float c1 = 0.f, c2 = 0.f;
    const int il = w;
    const int m  = lane;
    if (w < 4) {
        const int i = iu4 + il;
        #pragma unroll
        for (int g = 0; g < 4; ++g) {
            bias1[g] = bih0[i + g * HDIM] + bhh0[i + g * HDIM];
            bias2[g] = bih1[i + g * HDIM] + bhh1[i + g * HDIM];
        }
    }

    // ---- init: zero h^{(-1)} (frame 1) via coalesced stores + tag=1 ----
    if (w == 8) {
        uint2 z = {0u, 0u};
        st_cg8(ring1 + FRAME + oct4 * 512 + lane * 8 + coff, z);
        VM_DRAIN();
        if (lane == 0) tag_pub(tagA + bid, 1u);
    }
    if (w == 9) {
        uint2 z = {0u, 0u};
        st_cg8(ring2 + FRAME + oct4 * 512 + lane * 8 + coff, z);
        VM_DRAIN();
        if (lane == 0) tag_pub(tagB + bid, 1u);
    }

    for (int s = 0; s <= TDIM; ++s) {
        const f16* r1p = ring1 + (size_t)((s + 1) & 1) * FRAME;  // h1^{(s-1)}
        const f16* r2p = ring2 + (size_t)(s & 1) * FRAME;        // h2^{(s-2)}

        // ---- wait for h1^{(s-1)}: wave 0 polls all 256 tags in one read ----
        if (w == 0) tag_poll(tagA, lane, (unsigned)(s + 1));
        __syncthreads();   // S1 (also protects red/hbuf reuse from prev iter)

        // ---- acquire: invalidate L1+L2 so cached ring reads are fresh ----
        RING_ACQUIRE();

        // ---- A1 fragments (octet layout: one dwordx4 each, cacheable) ----
        f16x8 A1[2][4];
        #pragma unroll
        for (int j = 0; j < 2; ++j) {
            const int oct = (2 * w + j) * 4 + quad;
            #pragma unroll
            for (int mt = 0; mt < 4; ++mt)
                A1[j][mt] = ld_ca(r1p + oct * 512 + (mt * 16 + am) * 8);
        }
        VM_WAIT8(A1[0][0], A1[0][1], A1[0][2], A1[0][3],
                 A1[1][0], A1[1][1], A1[1][2], A1[1][3]);

        // ---- phase 1 (layer1) + layer2-Wih1 part (both consume A1) ----
        f32x4 acc[4], acc2[4];
        #pragma unroll
        for (int mt = 0; mt < 4; ++mt) {
            acc[mt]  = (f32x4){0.f, 0.f, 0.f, 0.f};
            acc2[mt] = (f32x4){0.f, 0.f, 0.f, 0.f};
        }
        #pragma unroll
        for (int j = 0; j < 2; ++j)
            #pragma unroll
            for (int mt = 0; mt < 4; ++mt) {
                acc[mt]  = MFMA16(A1[j][mt], B1h[j], acc[mt]);
                acc2[mt] = MFMA16(A1[j][mt], B2i[j], acc2[mt]);
            }
        if (w < 4) {
            const int ts = (s < TDIM) ? s : (TDIM - 1);
            const f16* xb = xP + (size_t)ts * BDIM * KIN;
            const int kx = w * 32 + quad * 8;
            #pragma unroll
            for (int mt = 0; mt < 4; ++mt) {
                f16x8 ax = *(const f16x8*)(xb + (size_t)(mt * 16 + am) * KIN + kx);
                acc[mt] = MFMA16(ax, B1x, acc[mt]);
            }
        }

        // ---- phase-1 reduction (8 partials) ----
        const int p = w & 7;
        if (w < 8) {
            #pragma unroll
            for (int mt = 0; mt < 4; ++mt)
                *(f32x4*)&red[(p * 4 + mt) * 324 + n * 20 + quad * 4] = acc[mt];
        }
        __syncthreads();   // S2
        if (w >= 8) {
            #pragma unroll
            for (int mt = 0; mt < 4; ++mt) {
                float* a = &red[(p * 4 + mt) * 324 + n * 20 + quad * 4];
                f32x4 v = *(f32x4*)a;
                *(f32x4*)a = v + acc[mt];
            }
        }
        __syncthreads();   // S3

        // ---- reduce1: owners -> h1 into LDS; wave 15 polls tagB ----
        if (w < 4 && s < TDIM) {
            const int mt = m >> 4, qm = m & 15;
            float g4[4];
            #pragma unroll
            for (int g = 0; g < 4; ++g) {
                float sum = bias1[g];
                #pragma unroll
                for (int pp = 0; pp < 8; ++pp)
                    sum += red[(pp * 4 + mt) * 324 + (il * 4 + g) * 20 + qm];
                g4[g] = sum;
            }
            float ig = sigm(g4[0]), fg = sigm(g4[1]);
            float gg = tanhf(g4[2]), og = sigm(g4[3]);
            c1 = fg * c1 + ig * gg;
            hbuf1[m * 4 + il] = (f16)(og * tanhf(c1));
        }
        // wait for h2^{(s-2)} (published end of superstep s-1 -> usually free)
        if (w == 15) tag_poll(tagB, lane, (unsigned)s);
        __syncthreads();   // S4: hbuf1 ready, tagB satisfied, red free

        // ---- wave 8: coalesced h1 store + tag publish (mid-iteration) ----
        if (w == 8 && s < TDIM) {
            uint2 v = *(const uint2*)&hbuf1[lane * 4];
            st_cg8(ring1 + (size_t)(s & 1) * FRAME + oct4 * 512 + lane * 8 + coff, v);
            VM_DRAIN();
            if (lane == 0) tag_pub(tagA + bid, (unsigned)(s + 2));
        }

        // ---- A2 fragments of h2^{(s-2)} (cacheable; covered by top fence) ----
        f16x8 A2[2][4];
        #pragma unroll
        for (int j = 0; j < 2; ++j) {
            const int oct = (2 * w + j) * 4 + quad;
            #pragma unroll
            for (int mt = 0; mt < 4; ++mt)
                A2[j][mt] = ld_ca(r2p + oct * 512 + (mt * 16 + am) * 8);
        }
        VM_WAIT8(A2[0][0], A2[0][1], A2[0][2], A2[0][3],
                 A2[1][0], A2[1][1], A2[1][2], A2[1][3]);
        #pragma unroll
        for (int j = 0; j < 2; ++j)
            #pragma unroll
            for (int mt = 0; mt < 4; ++mt)
                acc2[mt] = MFMA16(A2[j][mt], B2h[j], acc2[mt]);

        // ---- phase-2 reduction ----
        if (w < 8) {
            #pragma unroll
            for (int mt = 0; mt < 4; ++mt)
                *(f32x4*)&red[(p * 4 + mt) * 324 + n * 20 + quad * 4] = acc2[mt];
        }
        __syncthreads();   // S5
        if (w >= 8) {
            #pragma unroll
            for (int mt = 0; mt < 4; ++mt) {
                float* a = &red[(p * 4 + mt) * 324 + n * 20 + quad * 4];
                f32x4 v = *(f32x4*)a;
                *(f32x4*)a = v + acc2[mt];
            }
        }
        __syncthreads();   // S6

        // ---- reduce2: owners -> h2 into LDS ----
        if (w < 4 && s >= 1) {
            const int mt = m >> 4, qm = m & 15;
            float g4[4];
            #pragma unroll
            for (int g = 0; g < 4; ++g) {
                float sum = bias2[g];
                #pragma unroll
                for (int pp = 0; pp < 8; ++pp)
                    sum += red[(pp * 4 + mt) * 324 + (il * 4 + g) * 20 + qm];
                g4[g] = sum;
            }
            float ig = sigm(g4[0]), fg = sigm(g4[1]);
            float gg = tanhf(g4[2]), og = sigm(g4[3]);
            c2 = fg * c2 + ig * gg;
            hbuf2[m * 4 + il] = (f16)(og * tanhf(c2));
        }
        __syncthreads();   // S7: hbuf2 ready

        // ---- wave 9: coalesced h2 store + tag publish ----
        if (w == 9 && s >= 1) {
            uint2 v = *(const uint2*)&hbuf2[lane * 4];
            st_cg8(ring2 + (size_t)((s + 1) & 1) * FRAME + oct4 * 512 + lane * 8 + coff, v);
            VM_DRAIN();
            if (lane == 0) tag_pub(tagB + bid, (unsigned)(s + 1));
        }
    }
    // final h2^{(511)} is in ring2 frame 1
}

// ---------------------------------------------------------------------------
// out[b] = dot(h2[b, :], fc_w) + fc_b.  h2 in octet layout.
// ---------------------------------------------------------------------------
__global__ void fc_kernel(const f16* __restrict__ h2f,
                          const float* __restrict__ fcw,
                          const float* __restrict__ fcb,
                          float* __restrict__ out) {
    __shared__ float red[256];
    const int tid = threadIdx.x;
    const int b = tid >> 2, q = tid & 3;
    float s = 0.f;
    for (int oct = q * 32; oct < (q + 1) * 32; ++oct) {
        f16x8 v = *(const f16x8*)(h2f + oct * 512 + b * 8);
        #pragma unroll
        for (int j = 0; j < 8; ++j)
            s = fmaf((float)v[j], fcw[oct * 8 + j], s);
    }
    red[tid] = s;
    __syncthreads();
    if (q == 0)
        out[b] = red[tid] + red[tid + 1] + red[tid + 2] + red[tid + 3] + fcb[0];
}

// ---------------------------------------------------------------------------
extern "C" void kernel_launch(void* const* d_in, const int* in_sizes, int n_in,
                              void* d_out, int out_size, void* d_ws, size_t ws_size,
                              hipStream_t stream) {
    const float* x    = (const float*)d_in[0];
    const float* Wih0 = (const float*)d_in[1];
    const float* Whh0 = (const float*)d_in[2];
    const float* bih0 = (const float*)d_in[3];
    const float* bhh0 = (const float*)d_in[4];
    const float* Wih1 = (const float*)d_in[5];
    const float* Whh1 = (const float*)d_in[6];
    const float* bih1 = (const float*)d_in[7];
    const float* bhh1 = (const float*)d_in[8];
    const float* fcw  = (const float*)d_in[9];
    const float* fcb  = (const float*)d_in[10];
    float* out = (float*)d_out;

    // workspace (halfs): xP | Wc0 | Wh0 | Wc1 | Wh1 | ring1 | ring2 | tags
    f16* xPd   = (f16*)d_ws;
    f16* Wc0   = xPd + (size_t)TDIM * BDIM * KIN;
    f16* Wh0   = Wc0 + (size_t)4 * HDIM * KIN;
    f16* Wc1   = Wh0 + (size_t)4 * HDIM * HDIM;
    f16* Wh1   = Wc1 + (size_t)4 * HDIM * HDIM;
    f16* ring1 = Wh1 + (size_t)4 * HDIM * HDIM;
    f16* ring2 = ring1 + 2 * FRAME;
    unsigned* tagA = (unsigned*)(ring2 + 2 * FRAME);
    unsigned* tagB = tagA + 512;      // 2 KB apart from tagA

    hipMemsetAsync(tagA, 0, 4096, stream);
    {
        int n2 = 4 * HDIM * KIN / 2;
        cvt_w<<<dim3((n2 + 255) / 256), dim3(256), 0, stream>>>(Wih0, Wc0, n2);
        n2 = 4 * HDIM * HDIM / 2;
        cvt_w<<<dim3((n2 + 255) / 256), dim3(256), 0, stream>>>(Whh0, Wh0, n2);
        cvt_w<<<dim3((n2 + 255) / 256), dim3(256), 0, stream>>>(Whh1, Wh1, n2);
        cvt_w<<<dim3((n2 + 255) / 256), dim3(256), 0, stream>>>(Wih1, Wc1, n2);
    }
    {
        int np = TDIM * BDIM * (KIN / 2);
        cvt_x<<<dim3((np + 255) / 256), dim3(256), 0, stream>>>(x, xPd);
    }

    void* args[13];
    args[0]  = (void*)&xPd;
    args[1]  = (void*)&Wc0;
    args[2]  = (void*)&Wh0;
    args[3]  = (void*)&bih0;
    args[4]  = (void*)&bhh0;
    args[5]  = (void*)&Wc1;
    args[6]  = (void*)&Wh1;
    args[7]  = (void*)&bih1;
    args[8]  = (void*)&bhh1;
    args[9]  = (void*)&ring1;
    args[10] = (void*)&ring2;
    args[11] = (void*)&tagA;
    args[12] = (void*)&tagB;
    hipLaunchCooperativeKernel(reinterpret_cast<void*>(lstm_fused), dim3(NBLK), dim3(NTHR),
                               args, 0, stream);

    fc_kernel<<<dim3(1), dim3(256), 0, stream>>>(ring2 + FRAME, fcw, fcb, out);
}

// Round 4
// 3158.365 us; speedup vs baseline: 5.7149x; 5.7149x over previous
//
#include <hip/hip_runtime.h>
#include <math.h>

#define HDIM 1024
#define BDIM 64
#define TDIM 512
#define KIN  128
#define NBLK 256
#define NTHR 1024           // 16 waves
#define FRAME (HDIM * BDIM) // halfs per ring frame (2-deep rings)
#define SUBF  (HDIM * 32)   // halfs per 32-batch subframe (32768)

typedef _Float16 f16;
typedef __attribute__((ext_vector_type(2))) _Float16 f16x2;
typedef __attribute__((ext_vector_type(8))) _Float16 f16x8;
typedef __attribute__((ext_vector_type(4))) float f32x4;
typedef __attribute__((ext_vector_type(4))) unsigned u32x4;

#define MFMA16(a, b, c) __builtin_amdgcn_mfma_f32_16x16x32_f16((a), (b), (c), 0, 0, 0)

__device__ __forceinline__ float sigm(float x) { return 1.0f / (1.0f + expf(-x)); }

// ---------------------------------------------------------------------------
// r12: batch-split retile. Block (cg,bg) owns cols i0=cg*8..+7, batches
// b0=bg*32..+31 (256 blocks = 128 cg x 2 bg). Per-block ring ingest halves
// vs r9 (reads only its 32-batch subframe), cutting the measured L3-multicast
// BW term (r10 probe: B=4.1us of the 5.9us superstep) by 2x.
// Ring frame = 2 subframes; subframe layout (halfs):
//   idx(k, b32) = (k>>3)*256 + b32*8 + (k&7)   [128 octet-rows x 256 halfs]
// Block's 8 cols == octet-row cg of its subframe -> publish = one contiguous
// 512B wave-store. All ring I/O sc0sc1 (L3 coherence point, fence-free) —
// r11's cached-read+invalidate experiment regressed 6x (invalidate storm).
// ---------------------------------------------------------------------------
__device__ __forceinline__ f16x8 ld_cg(const f16* p) {
    f16x8 r;
    asm volatile("global_load_dwordx4 %0, %1, off sc0 sc1"
                 : "=v"(r) : "v"(p) : "memory");
    return r;
}
#define VM_WAIT4(r0, r1, r2, r3)                                         \
    asm volatile("s_waitcnt vmcnt(0)"                                    \
                 : "+v"(r0), "+v"(r1), "+v"(r2), "+v"(r3))

__device__ __forceinline__ void st_cg8(f16* p, uint2 v) {
    asm volatile("global_store_dwordx2 %0, %1, off sc0 sc1"
                 :: "v"(p), "v"(v) : "memory");
}
#define VM_DRAIN() asm volatile("s_waitcnt vmcnt(0)" ::: "memory")

// ---------------------------------------------------------------------------
// Tag sync: tag[bid] (4B) = published step tag, monotone, plain sc0sc1 store
// by producer lane0. Poller = one full wave: 64 lanes x dwordx4 = all 256
// tags in ONE coalesced 1KB read per poll round; exit when min >= target.
// ---------------------------------------------------------------------------
__device__ __forceinline__ void tag_pub(unsigned* tag, unsigned v) {
    asm volatile("global_store_dword %0, %1, off sc0 sc1"
                 :: "v"(tag), "v"(v) : "memory");
}
__device__ __forceinline__ void tag_poll(const unsigned* tags, int lane,
                                         unsigned tgt) {
    const unsigned* p = tags + lane * 4;
    for (;;) {
        u32x4 t;
        asm volatile("global_load_dwordx4 %0, %1, off sc0 sc1\n\t"
                     "s_waitcnt vmcnt(0)"
                     : "=v"(t) : "v"(p) : "memory");
        bool ok = (t.x >= tgt) && (t.y >= tgt) && (t.z >= tgt) && (t.w >= tgt);
        if (__all(ok)) break;
        __builtin_amdgcn_s_sleep(1);
    }
}

// ---------------------------------------------------------------------------
__global__ void cvt_w(const float* __restrict__ src, f16* __restrict__ dst, int n2) {
    int i = blockIdx.x * blockDim.x + threadIdx.x;
    if (i < n2) {
        float2 a = ((const float2*)src)[i];
        f16x2 o = {(f16)a.x, (f16)a.y};
        ((f16x2*)dst)[i] = o;
    }
}

// x[b][t][k] fp32 -> xP[t][b][k] fp16
__global__ void cvt_x(const float* __restrict__ x, f16* __restrict__ xP) {
    int P = blockIdx.x * blockDim.x + threadIdx.x;    // pair index
    if (P >= TDIM * BDIM * (KIN / 2)) return;
    int kp = P & 63;
    int b  = (P >> 6) & 63;
    int t  = P >> 12;
    float2 v = ((const float2*)x)[((size_t)b * TDIM + t) * (KIN / 2) + kp];
    f16x2 o = {(f16)v.x, (f16)v.y};
    ((f16x2*)xP)[((size_t)t * BDIM + b) * (KIN / 2) + kp] = o;
}

// ---------------------------------------------------------------------------
// Fused 2-layer LSTM — r9 pipeline/sync structure (16 waves, 16-way K-split,
// 8-partial LDS reduce, 2-deep rings, LDS-staged coalesced publishes, tag
// sync), retiled to N=32 gate-rows (8 cols) x M=32 batches per block.
// Tag convention: after publishing h1^{(t)}: tagA[bid] = t+2 (init t=-1 -> 1);
//                 after publishing h2^{(t)}: tagB[bid] = t+2.
// Waits: top of s needs h1^{(s-1)} -> tagA >= s+1;
//        mid-body needs h2^{(s-2)} -> tagB >= s.
// ---------------------------------------------------------------------------
__global__ void __launch_bounds__(NTHR, 4) lstm_fused(
    const f16* __restrict__ xP,
    const f16* __restrict__ Wc0, const f16* __restrict__ Wh0,
    const float* __restrict__ bih0, const float* __restrict__ bhh0,
    const f16* __restrict__ Wc1, const f16* __restrict__ Wh1,
    const float* __restrict__ bih1, const float* __restrict__ bhh1,
    f16* ring1, f16* ring2, unsigned* tagA, unsigned* tagB) {

    __shared__ float red[32 * 324 + 16];          // ~41.6 KB padded slots
    __shared__ __align__(16) f16 hbuf1[32 * 8];   // owner h1 staging [b32][c]
    __shared__ __align__(16) f16 hbuf2[32 * 8];

    const int tid  = threadIdx.x;
    const int lane = tid & 63;
    const int w    = __builtin_amdgcn_readfirstlane(tid >> 6);   // 0..15
    const int bid  = (int)blockIdx.x;
    const int cg   = __builtin_amdgcn_readfirstlane(bid & 127);  // col group
    const int bg   = __builtin_amdgcn_readfirstlane(bid >> 7);   // batch group
    const int i0   = cg * 8;        // first owned column
    const int b0   = bg * 32;       // first owned batch

    const int n    = lane & 15;
    const int quad = lane >> 4;
    const int am   = lane & 15;
    const int kq   = quad * 8;

    // weight rows for the two N-tiles: row(nt,n) = i0 + nt*4 + (n>>2) + (n&3)*H
    int wr[2];
    #pragma unroll
    for (int nt = 0; nt < 2; ++nt)
        wr[nt] = i0 + nt * 4 + (n >> 2) + (n & 3) * HDIM;

    // ---- preload stationary weight fragments ([j][nt]) ----
    f16x8 B1x[2];
    f16x8 B1h[2][2], B2i[2][2], B2h[2][2];
    {
        if (w < 4)
            #pragma unroll
            for (int nt = 0; nt < 2; ++nt)
                B1x[nt] = *(const f16x8*)(Wc0 + (size_t)wr[nt] * KIN + w * 32 + kq);
        #pragma unroll
        for (int j = 0; j < 2; ++j) {
            const int ks = (2 * w + j) * 32 + kq;
            #pragma unroll
            for (int nt = 0; nt < 2; ++nt) {
                B1h[j][nt] = *(const f16x8*)(Wh0 + (size_t)wr[nt] * HDIM + ks);
                B2i[j][nt] = *(const f16x8*)(Wc1 + (size_t)wr[nt] * HDIM + ks);
                B2h[j][nt] = *(const f16x8*)(Wh1 + (size_t)wr[nt] * HDIM + ks);
            }
        }
    }

    // ---- owner state (waves 0..3): lane -> (c = w*2 + lane>>5, b32 = lane&31)
    float bias1[4], bias2[4];
    float c1 = 0.f, c2 = 0.f;
    const int il   = w;
    const int cO   = il * 2 + (lane >> 5);     // owned col within 8
    const int b32O = lane & 31;                // owned batch within group
    const int mtO  = (lane >> 4) & 1;
    const int qmO  = lane & 15;
    const int ntO  = il >> 1;
    const int nbO  = ((il & 1) * 2 + (lane >> 5)) * 4;  // n = nbO + g
    if (w < 4) {
        const int i = i0 + cO;
        #pragma unroll
        for (int g = 0; g < 4; ++g) {
            bias1[g] = bih0[i + g * HDIM] + bhh0[i + g * HDIM];
            bias2[g] = bih1[i + g * HDIM] + bhh1[i + g * HDIM];
        }
    }

    // ---- init: zero own region of h^{(-1)} (frame 1) + tag=1 ----
    if (w == 8) {
        uint2 z = {0u, 0u};
        st_cg8(ring1 + FRAME + bg * SUBF + cg * 256 + lane * 4, z);
        VM_DRAIN();
        if (lane == 0) tag_pub(tagA + bid, 1u);
    }
    if (w == 9) {
        uint2 z = {0u, 0u};
        st_cg8(ring2 + FRAME + bg * SUBF + cg * 256 + lane * 4, z);
        VM_DRAIN();
        if (lane == 0) tag_pub(tagB + bid, 1u);
    }

    for (int s = 0; s <= TDIM; ++s) {
        const f16* r1p = ring1 + (size_t)((s + 1) & 1) * FRAME + bg * SUBF; // h1^{(s-1)}
        const f16* r2p = ring2 + (size_t)(s & 1) * FRAME + bg * SUBF;       // h2^{(s-2)}

        // ---- wait for h1^{(s-1)}: wave 0 polls all 256 tags in one read ----
        if (w == 0) tag_poll(tagA, lane, (unsigned)(s + 1));
        __syncthreads();   // S1 (also protects red/hbuf reuse from prev iter)

        // ---- A1 fragments: [j][mt], one dwordx4 each (4 loads/wave) ----
        f16x8 A1[2][2];
        #pragma unroll
        for (int j = 0; j < 2; ++j) {
            const int oct = (2 * w + j) * 4 + quad;
            #pragma unroll
            for (int mt = 0; mt < 2; ++mt)
                A1[j][mt] = ld_cg(r1p + oct * 256 + (mt * 16 + am) * 8);
        }
        VM_WAIT4(A1[0][0], A1[0][1], A1[1][0], A1[1][1]);

        // ---- phase 1 (layer1) + layer2-Wih1 part (both consume A1) ----
        f32x4 acc[2][2], acc2[2][2];
        #pragma unroll
        for (int mt = 0; mt < 2; ++mt)
            #pragma unroll
            for (int nt = 0; nt < 2; ++nt) {
                acc[mt][nt]  = (f32x4){0.f, 0.f, 0.f, 0.f};
                acc2[mt][nt] = (f32x4){0.f, 0.f, 0.f, 0.f};
            }
        #pragma unroll
        for (int j = 0; j < 2; ++j)
            #pragma unroll
            for (int nt = 0; nt < 2; ++nt)
                #pragma unroll
                for (int mt = 0; mt < 2; ++mt) {
                    acc[mt][nt]  = MFMA16(A1[j][mt], B1h[j][nt], acc[mt][nt]);
                    acc2[mt][nt] = MFMA16(A1[j][mt], B2i[j][nt], acc2[mt][nt]);
                }
        if (w < 4) {
            const int ts = (s < TDIM) ? s : (TDIM - 1);
            const f16* xb = xP + (size_t)ts * BDIM * KIN;
            const int kx = w * 32 + kq;
            f16x8 ax[2];
            #pragma unroll
            for (int mt = 0; mt < 2; ++mt)
                ax[mt] = *(const f16x8*)(xb + (size_t)(b0 + mt * 16 + am) * KIN + kx);
            #pragma unroll
            for (int nt = 0; nt < 2; ++nt)
                #pragma unroll
                for (int mt = 0; mt < 2; ++mt)
                    acc[mt][nt] = MFMA16(ax[mt], B1x[nt], acc[mt][nt]);
        }

        // ---- phase-1 reduction (8 partials; tile id = mt*2+nt) ----
        const int p = w & 7;
        if (w < 8) {
            #pragma unroll
            for (int mt = 0; mt < 2; ++mt)
                #pragma unroll
                for (int nt = 0; nt < 2; ++nt)
                    *(f32x4*)&red[(p * 4 + mt * 2 + nt) * 324 + n * 20 + quad * 4] = acc[mt][nt];
        }
        __syncthreads();   // S2
        if (w >= 8) {
            #pragma unroll
            for (int mt = 0; mt < 2; ++mt)
                #pragma unroll
                for (int nt = 0; nt < 2; ++nt) {
                    float* a = &red[(p * 4 + mt * 2 + nt) * 324 + n * 20 + quad * 4];
                    f32x4 v = *(f32x4*)a;
                    *(f32x4*)a = v + acc[mt][nt];
                }
        }
        __syncthreads();   // S3

        // ---- reduce1: owners -> h1 into LDS; wave 15 polls tagB ----
        if (w < 4 && s < TDIM) {
            float g4[4];
            #pragma unroll
            for (int g = 0; g < 4; ++g) {
                float sum = bias1[g];
                #pragma unroll
                for (int pp = 0; pp < 8; ++pp)
                    sum += red[(pp * 4 + mtO * 2 + ntO) * 324 + (nbO + g) * 20 + qmO];
                g4[g] = sum;
            }
            float ig = sigm(g4[0]), fg = sigm(g4[1]);
            float gg = tanhf(g4[2]), og = sigm(g4[3]);
            c1 = fg * c1 + ig * gg;
            hbuf1[b32O * 8 + cO] = (f16)(og * tanhf(c1));
        }
        // wait for h2^{(s-2)} (published end of superstep s-1 -> usually free)
        if (w == 15) tag_poll(tagB, lane, (unsigned)s);
        __syncthreads();   // S4: hbuf1 ready, tagB satisfied, red free

        // ---- wave 8: coalesced 512B h1 publish + tag (mid-iteration) ----
        if (w == 8 && s < TDIM) {
            uint2 v = *(const uint2*)&hbuf1[lane * 4];
            st_cg8(ring1 + (size_t)(s & 1) * FRAME + bg * SUBF + cg * 256 + lane * 4, v);
            VM_DRAIN();
            if (lane == 0) tag_pub(tagA + bid, (unsigned)(s + 2));
        }

        // ---- A2 fragments of h2^{(s-2)} ----
        f16x8 A2[2][2];
        #pragma unroll
        for (int j = 0; j < 2; ++j) {
            const int oct = (2 * w + j) * 4 + quad;
            #pragma unroll
            for (int mt = 0; mt < 2; ++mt)
                A2[j][mt] = ld_cg(r2p + oct * 256 + (mt * 16 + am) * 8);
        }
        VM_WAIT4(A2[0][0], A2[0][1], A2[1][0], A2[1][1]);
        #pragma unroll
        for (int j = 0; j < 2; ++j)
            #pragma unroll
            for (int nt = 0; nt < 2; ++nt)
                #pragma unroll
                for (int mt = 0; mt < 2; ++mt)
                    acc2[mt][nt] = MFMA16(A2[j][mt], B2h[j][nt], acc2[mt][nt]);

        // ---- phase-2 reduction ----
        if (w < 8) {
            #pragma unroll
            for (int mt = 0; mt < 2; ++mt)
                #pragma unroll
                for (int nt = 0; nt < 2; ++nt)
                    *(f32x4*)&red[(p * 4 + mt * 2 + nt) * 324 + n * 20 + quad * 4] = acc2[mt][nt];
        }
        __syncthreads();   // S5
        if (w >= 8) {
            #pragma unroll
            for (int mt = 0; mt < 2; ++mt)
                #pragma unroll
                for (int nt = 0; nt < 2; ++nt) {
                    float* a = &red[(p * 4 + mt * 2 + nt) * 324 + n * 20 + quad * 4];
                    f32x4 v = *(f32x4*)a;
                    *(f32x4*)a = v + acc2[mt][nt];
                }
        }
        __syncthreads();   // S6

        // ---- reduce2: owners -> h2 into LDS ----
        if (w < 4 && s >= 1) {
            float g4[4];
            #pragma unroll
            for (int g = 0; g < 4; ++g) {
                float sum = bias2[g];
                #pragma unroll
                for (int pp = 0; pp < 8; ++pp)
                    sum += red[(pp * 4 + mtO * 2 + ntO) * 324 + (nbO + g) * 20 + qmO];
                g4[g] = sum;
            }
            float ig = sigm(g4[0]), fg = sigm(g4[1]);
            float gg = tanhf(g4[2]), og = sigm(g4[3]);
            c2 = fg * c2 + ig * gg;
            hbuf2[b32O * 8 + cO] = (f16)(og * tanhf(c2));
        }
        __syncthreads();   // S7: hbuf2 ready

        // ---- wave 9: coalesced 512B h2 publish + tag ----
        if (w == 9 && s >= 1) {
            uint2 v = *(const uint2*)&hbuf2[lane * 4];
            st_cg8(ring2 + (size_t)((s + 1) & 1) * FRAME + bg * SUBF + cg * 256 + lane * 4, v);
            VM_DRAIN();
            if (lane == 0) tag_pub(tagB + bid, (unsigned)(s + 1));
        }
    }
    // final h2^{(511)} is in ring2 frame 1
}

// ---------------------------------------------------------------------------
// out[b] = dot(h2[b, :], fc_w) + fc_b.  h2 in subframe/octet layout:
//   idx(k, b) = (b>>5)*SUBF + (k>>3)*256 + (b&31)*8 + (k&7)
// ---------------------------------------------------------------------------
__global__ void fc_kernel(const f16* __restrict__ h2f,
                          const float* __restrict__ fcw,
                          const float* __restrict__ fcb,
                          float* __restrict__ out) {
    __shared__ float red[256];
    const int tid = threadIdx.x;
    const int b = tid >> 2, q = tid & 3;
    const int base = (b >> 5) * SUBF + (b & 31) * 8;
    float s = 0.f;
    for (int oct = q * 32; oct < (q + 1) * 32; ++oct) {
        f16x8 v = *(const f16x8*)(h2f + base + oct * 256);
        #pragma unroll
        for (int j = 0; j < 8; ++j)
            s = fmaf((float)v[j], fcw[oct * 8 + j], s);
    }
    red[tid] = s;
    __syncthreads();
    if (q == 0)
        out[b] = red[tid] + red[tid + 1] + red[tid + 2] + red[tid + 3] + fcb[0];
}

// ---------------------------------------------------------------------------
extern "C" void kernel_launch(void* const* d_in, const int* in_sizes, int n_in,
                              void* d_out, int out_size, void* d_ws, size_t ws_size,
                              hipStream_t stream) {
    const float* x    = (const float*)d_in[0];
    const float* Wih0 = (const float*)d_in[1];
    const float* Whh0 = (const float*)d_in[2];
    const float* bih0 = (const float*)d_in[3];
    const float* bhh0 = (const float*)d_in[4];
    const float* Wih1 = (const float*)d_in[5];
    const float* Whh1 = (const float*)d_in[6];
    const float* bih1 = (const float*)d_in[7];
    const float* bhh1 = (const float*)d_in[8];
    const float* fcw  = (const float*)d_in[9];
    const float* fcb  = (const float*)d_in[10];
    float* out = (float*)d_out;

    // workspace (halfs): xP | Wc0 | Wh0 | Wc1 | Wh1 | ring1 | ring2 | tags
    f16* xPd   = (f16*)d_ws;
    f16* Wc0   = xPd + (size_t)TDIM * BDIM * KIN;
    f16* Wh0   = Wc0 + (size_t)4 * HDIM * KIN;
    f16* Wc1   = Wh0 + (size_t)4 * HDIM * HDIM;
    f16* Wh1   = Wc1 + (size_t)4 * HDIM * HDIM;
    f16* ring1 = Wh1 + (size_t)4 * HDIM * HDIM;
    f16* ring2 = ring1 + 2 * FRAME;
    unsigned* tagA = (unsigned*)(ring2 + 2 * FRAME);
    unsigned* tagB = tagA + 512;      // 2 KB apart from tagA

    hipMemsetAsync(tagA, 0, 4096, stream);
    {
        int n2 = 4 * HDIM * KIN / 2;
        cvt_w<<<dim3((n2 + 255) / 256), dim3(256), 0, stream>>>(Wih0, Wc0, n2);
        n2 = 4 * HDIM * HDIM / 2;
        cvt_w<<<dim3((n2 + 255) / 256), dim3(256), 0, stream>>>(Whh0, Wh0, n2);
        cvt_w<<<dim3((n2 + 255) / 256), dim3(256), 0, stream>>>(Whh1, Wh1, n2);
        cvt_w<<<dim3((n2 + 255) / 256), dim3(256), 0, stream>>>(Wih1, Wc1, n2);
    }
    {
        int np = TDIM * BDIM * (KIN / 2);
        cvt_x<<<dim3((np + 255) / 256), dim3(256), 0, stream>>>(x, xPd);
    }

    void* args[13];
    args[0]  = (void*)&xPd;
    args[1]  = (void*)&Wc0;
    args[2]  = (void*)&Wh0;
    args[3]  = (void*)&bih0;
    args[4]  = (void*)&bhh0;
    args[5]  = (void*)&Wc1;
    args[6]  = (void*)&Wh1;
    args[7]  = (void*)&bih1;
    args[8]  = (void*)&bhh1;
    args[9]  = (void*)&ring1;
    args[10] = (void*)&ring2;
    args[11] = (void*)&tagA;
    args[12] = (void*)&tagB;
    hipLaunchCooperativeKernel(reinterpret_cast<void*>(lstm_fused), dim3(NBLK), dim3(NTHR),
                               args, 0, stream);

    fc_kernel<<<dim3(1), dim3(256), 0, stream>>>(ring2 + FRAME, fcw, fcb, out);
}